// Round 17
// baseline (624.261 us; speedup 1.0000x reference)
//
#include <hip/hip_runtime.h>

typedef unsigned short u16;
typedef __attribute__((ext_vector_type(4))) unsigned short u16x4;
typedef __attribute__((ext_vector_type(8))) unsigned short u16x8;
typedef __attribute__((ext_vector_type(4))) float f32x4;
typedef __attribute__((ext_vector_type(8))) __bf16 bf16x8;

#define NN 16000
#define NE 64000

__device__ __forceinline__ float bf2f(u16 b) {
  union { unsigned int u; float f; } v; v.u = ((unsigned int)b) << 16; return v.f;
}
__device__ __forceinline__ u16 f2bf(float x) {
  union { float f; unsigned int u; } v; v.f = x;
  unsigned int r = v.u + 0x7FFFu + ((v.u >> 16) & 1u);
  return (u16)(r >> 16);
}

// ---------------- node init: f32 working copy + bf16 mirror ----------------
__global__ void cast_init(const float* __restrict__ in, float* __restrict__ outf,
                          u16* __restrict__ outb, int n4) {
  for (int i = blockIdx.x * blockDim.x + threadIdx.x; i < n4; i += gridDim.x * blockDim.x) {
    f32x4 v = ((const f32x4*)in)[i];
    u16x4 b;
#pragma unroll
    for (int j = 0; j < 4; ++j) b[j] = f2bf(v[j]);
    ((f32x4*)outf)[i] = v;
    ((u16x4*)outb)[i] = b;
  }
}

// ---------------- edge init: bf16 state only ----------------
__global__ void cast_bf(const float* __restrict__ in, u16* __restrict__ outb, int n4) {
  for (int i = blockIdx.x * blockDim.x + threadIdx.x; i < n4; i += gridDim.x * blockDim.x) {
    f32x4 v = ((const f32x4*)in)[i];
    u16x4 b;
#pragma unroll
    for (int j = 0; j < 4; ++j) b[j] = f2bf(v[j]);
    ((u16x4*)outb)[i] = b;
  }
}

// ---------------- CSR build ----------------
__global__ void deg_hist(const int* __restrict__ dst, int* __restrict__ deg) {
  int e = blockIdx.x * 256 + threadIdx.x;
  if (e < NE) atomicAdd(&deg[dst[e]], 1);
}

__global__ __launch_bounds__(1024) void scan_deg(const int* __restrict__ deg,
                                                 int* __restrict__ row_ptr,
                                                 int* __restrict__ cursor) {
  __shared__ int lds[1024];
  int t = threadIdx.x;
  int base = t * 16;
  int v[16];
  int s = 0;
#pragma unroll
  for (int j = 0; j < 16; ++j) {
    int idx = base + j;
    v[j] = idx < NN ? deg[idx] : 0;
    s += v[j];
  }
  lds[t] = s;
  __syncthreads();
  for (int d = 1; d < 1024; d <<= 1) {
    int x = t >= d ? lds[t - d] : 0;
    __syncthreads();
    lds[t] += x;
    __syncthreads();
  }
  int run = lds[t] - s;
  for (int j = 0; j < 16; ++j) {
    int idx = base + j;
    if (idx < NN) { row_ptr[idx] = run; cursor[idx] = run; run += v[j]; }
  }
  if (t == 1023) row_ptr[NN] = run;
}

__global__ void csr_fill(const int* __restrict__ src, const int* __restrict__ dst,
                         int* __restrict__ cursor, int* __restrict__ cs_e,
                         int* __restrict__ cs_src, int* __restrict__ cs_dst) {
  int e = blockIdx.x * 256 + threadIdx.x;
  if (e >= NE) return;
  int d = dst[e];
  int pos = atomicAdd(&cursor[d], 1);
  cs_e[pos] = e;
  cs_src[pos] = src[e];
  cs_dst[pos] = d;
}

// ---- weight transpose + bf16 cast ----
__global__ void transpose4(const float* __restrict__ W0, const float* __restrict__ W1,
                           const float* __restrict__ W2, const float* __restrict__ W3,
                           int ld, int osz, u16* __restrict__ WT) {
  __shared__ float t[16][17];
  int z = blockIdx.z;
  const float* W = z == 0 ? W0 : (z == 1 ? W1 : (z == 2 ? W2 : W3));
  u16* O = WT + (size_t)z * osz;
  int n0 = blockIdx.x * 16, k0 = blockIdx.y * 16;
  int tx = threadIdx.x, ty = threadIdx.y;
  t[ty][tx] = W[(size_t)(k0 + ty) * ld + n0 + tx];
  __syncthreads();
  O[(size_t)(n0 + ty) * 256 + k0 + tx] = f2bf(t[tx][ty]);
}

// ---- final-weight transpose with head-interleave: col n=h*256+c -> j=c*8+h ----
__global__ void transpose4p(const float* __restrict__ W0, const float* __restrict__ W1,
                            const float* __restrict__ W2, const float* __restrict__ W3,
                            u16* __restrict__ WT) {
  __shared__ float t[16][17];
  int z = blockIdx.z;
  const float* W = z == 0 ? W0 : (z == 1 ? W1 : (z == 2 ? W2 : W3));
  u16* O = WT + (size_t)z * 524288;
  int n0 = blockIdx.x * 16, k0 = blockIdx.y * 16;
  int tx = threadIdx.x, ty = threadIdx.y;
  t[ty][tx] = W[(size_t)(k0 + ty) * 2048 + n0 + tx];
  __syncthreads();
  int n = n0 + ty;
  int j = (n & 255) * 8 + (n >> 8);
  O[(size_t)j * 256 + k0 + tx] = f2bf(t[tx][ty]);
}

// ---- bias/attn head-interleave permute ----
__global__ void permute_ba(const float* __restrict__ bias, const float* __restrict__ attn,
                           float* __restrict__ bias_p, float* __restrict__ attn_p) {
  int n = blockIdx.x * 256 + threadIdx.x;
  int j = (n & 255) * 8 + (n >> 8);
  bias_p[j] = bias[n];
  attn_p[j] = attn[n];
}

// ------------- bf16 GEMM (r9 proven form): 2-phase BK=64, unchanged -------------
__global__ __launch_bounds__(256) void gemm_abt(
    const u16* __restrict__ A,
    const u16* __restrict__ BT0, const u16* __restrict__ BT1, const u16* __restrict__ BT2,
    u16* __restrict__ C0, u16* __restrict__ C1, u16* __restrict__ C2, int ldc) {
  const int bz = blockIdx.z;
  const u16* BT = bz == 0 ? BT0 : (bz == 1 ? BT1 : BT2);
  u16* C = bz == 0 ? C0 : (bz == 1 ? C1 : C2);
  const int nx = gridDim.x;
  const int nwg = nx * gridDim.y;
  int bid = blockIdx.y * nx + blockIdx.x;
  int q = nwg >> 3, r = nwg & 7;
  int xcd = bid & 7, idx = bid >> 3;
  int wg = (xcd < r) ? (xcd * (q + 1) + idx) : (r * (q + 1) + (xcd - r) * q + idx);
  const int m0 = (wg / nx) * 128;
  const int n0 = (wg % nx) * 128;
  __shared__ __attribute__((aligned(16))) char smem[69632];
  u16* lA = (u16*)smem;
  u16* lB = (u16*)(smem + 32768);
  const int tid = threadIdx.x;
  const int lane = tid & 63;
  const int wid = tid >> 6;
  const int wr = (wid >> 1) * 64;
  const int wc = (wid & 1) * 64;
  const int srow = tid >> 3;
  const int sdst = (tid & 7) * 8;
  const int ssrc = (((tid & 7) ^ (srow & 7))) * 8;
  const int sx = (lane >> 4) ^ (lane & 7);
  f32x4 acc[4][4] = {};
#define STAGE(buf, kb)                                                                         \
  {                                                                                            \
    _Pragma("unroll") for (int i = 0; i < 4; ++i) {                                            \
      const int row = srow + i * 32;                                                           \
      __builtin_amdgcn_global_load_lds(                                                        \
          (const __attribute__((address_space(1))) void*)(A + (size_t)(m0 + row) * 256 + (kb) + ssrc), \
          (__attribute__((address_space(3))) void*)(lA + (buf) * 8192 + row * 64 + sdst), 16, 0, 0); \
      __builtin_amdgcn_global_load_lds(                                                        \
          (const __attribute__((address_space(1))) void*)(BT + (size_t)(n0 + row) * 256 + (kb) + ssrc), \
          (__attribute__((address_space(3))) void*)(lB + (buf) * 8192 + row * 64 + sdst), 16, 0, 0); \
    }                                                                                          \
  }
  STAGE(0, 0)
  __syncthreads();
#pragma unroll
  for (int t = 0; t < 4; ++t) {
    if (t < 3) STAGE((t + 1) & 1, (t + 1) * 64)
    const u16* pA = lA + (t & 1) * 8192;
    const u16* pB = lB + (t & 1) * 8192;
#pragma unroll
    for (int kk = 0; kk < 2; ++kk) {
      const int sw = ((kk << 2) ^ sx) * 8;
      bf16x8 af[4], bfr[4];
#pragma unroll
      for (int m = 0; m < 4; ++m)
        af[m] = *(const bf16x8*)(pA + (wr + m * 16 + (lane & 15)) * 64 + sw);
#pragma unroll
      for (int n = 0; n < 4; ++n)
        bfr[n] = *(const bf16x8*)(pB + (wc + n * 16 + (lane & 15)) * 64 + sw);
#pragma unroll
      for (int m = 0; m < 4; ++m)
#pragma unroll
        for (int n = 0; n < 4; ++n)
          acc[m][n] = __builtin_amdgcn_mfma_f32_16x16x32_bf16(af[m], bfr[n], acc[m][n], 0, 0, 0);
    }
    __syncthreads();
  }
#undef STAGE
  const int cr = (lane >> 4) * 4;
  const int cc = lane & 15;
  float* stg = (float*)smem + wid * (64 * 68);
#pragma unroll
  for (int m = 0; m < 4; ++m)
#pragma unroll
    for (int n = 0; n < 4; ++n)
#pragma unroll
      for (int j = 0; j < 4; ++j)
        stg[(m * 16 + cr + j) * 68 + n * 16 + cc] = acc[m][n][j];
  const int rr = lane >> 3;
  const int c0 = (lane & 7) * 8;
#pragma unroll
  for (int p = 0; p < 8; ++p) {
    int row = p * 8 + rr;
    f32x4 v0 = *(const f32x4*)(stg + row * 68 + c0);
    f32x4 v1 = *(const f32x4*)(stg + row * 68 + c0 + 4);
    u16x8 o;
#pragma unroll
    for (int i = 0; i < 4; ++i) { o[i] = f2bf(v0[i]); o[4 + i] = f2bf(v1[i]); }
    *(u16x8*)(&C[(size_t)(m0 + wr + row) * ldc + (n0 + wc + c0)]) = o;
  }
}

// === fused kernels: BK=32 (r10-validated swizzle), bf16 C-staging, 34.8KB LDS -> 4 blocks/CU ===

// ------------- FUSED hidden f-GEMM, CSR-ordered edges -------------
__global__ __launch_bounds__(256) void gemm_fused_hidden(
    const u16* __restrict__ A, const u16* __restrict__ BT, const u16* __restrict__ t3,
    const int* __restrict__ cs_e, const int* __restrict__ cs_src, const int* __restrict__ cs_dst,
    const float* __restrict__ bias, const float* __restrict__ attn,
    u16* __restrict__ f_new, float* __restrict__ exb) {
  const int nx = gridDim.x;
  const int nwg = nx * gridDim.y;
  int bid = blockIdx.y * nx + blockIdx.x;
  int q = nwg >> 3, r = nwg & 7;
  int xcd = bid & 7, idx = bid >> 3;
  int wg = (xcd < r) ? (xcd * (q + 1) + idx) : (r * (q + 1) + (xcd - r) * q + idx);
  const int m0 = (wg / nx) * 128;
  const int n0 = (wg % nx) * 128;
  __shared__ __attribute__((aligned(16))) char smem[34816];
  u16* lA = (u16*)smem;              // [2][4096]
  u16* lB = (u16*)(smem + 16384);    // [2][4096]
  const int tid = threadIdx.x;
  const int lane = tid & 63;
  const int wid = tid >> 6;
  const int wr = (wid >> 1) * 64;
  const int wc = (wid & 1) * 64;
  const int srow = tid >> 2;                               // BK=32 staging (r10 swizzle)
  const int sdst = (tid & 3) * 8;
  const int ssrc = ((tid & 3) ^ ((tid >> 3) & 3)) * 8;
  const int rslot = ((lane >> 4) ^ ((lane >> 1) & 3)) * 8;
  int cse_s[2];
#pragma unroll
  for (int i = 0; i < 2; ++i) cse_s[i] = cs_e[m0 + srow + i * 64];
  const int rr = lane >> 3;
  const int c0e = (lane & 7) * 8;
  const int j0 = n0 + wc + c0e;
  const int head = j0 >> 5;
  int ep[8];
  u16x8 va8[8], vb8[8], fs8[8];
#pragma unroll
  for (int p = 0; p < 8; ++p) {
    int pos = m0 + wr + p * 8 + rr;
    int e = cs_e[pos];
    int is = cs_src[pos], id = cs_dst[pos];
    ep[p] = e;
    va8[p] = *(const u16x8*)(t3 + (size_t)is * 768 + j0);
    vb8[p] = *(const u16x8*)(t3 + (size_t)id * 768 + 256 + j0);
    fs8[p] = *(const u16x8*)(A + (size_t)e * 256 + j0);
  }
  f32x4 acc[4][4] = {};
#define STAGE(buf, kb)                                                                         \
  {                                                                                            \
    _Pragma("unroll") for (int i = 0; i < 2; ++i) {                                            \
      const int row = srow + i * 64;                                                           \
      __builtin_amdgcn_global_load_lds(                                                        \
          (const __attribute__((address_space(1))) void*)(A + (size_t)cse_s[i] * 256 + (kb) + ssrc), \
          (__attribute__((address_space(3))) void*)(lA + (buf) * 4096 + row * 32 + sdst), 16, 0, 0); \
      __builtin_amdgcn_global_load_lds(                                                        \
          (const __attribute__((address_space(1))) void*)(BT + (size_t)(n0 + row) * 256 + (kb) + ssrc), \
          (__attribute__((address_space(3))) void*)(lB + (buf) * 4096 + row * 32 + sdst), 16, 0, 0); \
    }                                                                                          \
  }
  STAGE(0, 0)
  __syncthreads();
#pragma unroll
  for (int t = 0; t < 8; ++t) {
    if (t < 7) STAGE((t + 1) & 1, (t + 1) * 32)
    const u16* pA = lA + (t & 1) * 4096;
    const u16* pB = lB + (t & 1) * 4096;
    bf16x8 af[4], bfr[4];
#pragma unroll
    for (int m = 0; m < 4; ++m)
      af[m] = *(const bf16x8*)(pA + (wr + m * 16 + (lane & 15)) * 32 + rslot);
#pragma unroll
    for (int n = 0; n < 4; ++n)
      bfr[n] = *(const bf16x8*)(pB + (wc + n * 16 + (lane & 15)) * 32 + rslot);
#pragma unroll
    for (int m = 0; m < 4; ++m)
#pragma unroll
      for (int n = 0; n < 4; ++n)
        acc[m][n] = __builtin_amdgcn_mfma_f32_16x16x32_bf16(af[m], bfr[n], acc[m][n], 0, 0, 0);
    __syncthreads();
  }
#undef STAGE
  // bf16 C-staging (per-wave region overlaying the K-loop buffers; post-barrier safe)
  const int cr = (lane >> 4) * 4;
  const int cc = lane & 15;
  u16* stg = (u16*)smem + wid * (64 * 68);
#pragma unroll
  for (int m = 0; m < 4; ++m)
#pragma unroll
    for (int n = 0; n < 4; ++n)
#pragma unroll
      for (int j = 0; j < 4; ++j)
        stg[(m * 16 + cr + j) * 68 + n * 16 + cc] = f2bf(acc[m][n][j]);
  f32x4 bias0 = *(const f32x4*)(bias + j0);
  f32x4 bias1 = *(const f32x4*)(bias + j0 + 4);
  f32x4 attn0 = *(const f32x4*)(attn + j0);
  f32x4 attn1 = *(const f32x4*)(attn + j0 + 4);
#pragma unroll
  for (int p = 0; p < 8; ++p) {
    int row = p * 8 + rr;
    int pos = m0 + wr + row;
    u16x4 w0 = *(const u16x4*)(stg + row * 68 + c0e);
    u16x4 w1 = *(const u16x4*)(stg + row * 68 + c0e + 4);
    float lp = 0.f;
    u16x8 o;
#pragma unroll
    for (int h = 0; h < 4; ++h) {
      float t0 = bf2f(w0[h]) + bf2f(va8[p][h]) + bf2f(vb8[p][h]) + bias0[h];
      t0 = t0 > 0.f ? t0 : 0.01f * t0;
      lp += t0 * attn0[h];
      float e0 = t0 > 0.f ? t0 : expm1f(t0);
      o[h] = f2bf(bf2f(fs8[p][h]) + e0);
      float t1 = bf2f(w1[h]) + bf2f(va8[p][4 + h]) + bf2f(vb8[p][4 + h]) + bias1[h];
      t1 = t1 > 0.f ? t1 : 0.01f * t1;
      lp += t1 * attn1[h];
      float e1 = t1 > 0.f ? t1 : expm1f(t1);
      o[4 + h] = f2bf(bf2f(fs8[p][4 + h]) + e1);
    }
    *(u16x8*)(&f_new[(size_t)ep[p] * 256 + j0]) = o;
    lp += __shfl_xor(lp, 1);
    lp += __shfl_xor(lp, 2);
    lp = fminf(fmaxf(lp, -30.f), 30.f);
    if ((lane & 3) == 0) exb[(size_t)pos * 8 + head] = expf(lp);
  }
}

// ------------- FUSED final f-GEMM, CSR-ordered edges, prologue-prefetched -------------
__global__ __launch_bounds__(256) void gemm_fused_final(
    int p0, const u16* __restrict__ A, const u16* __restrict__ BT,
    const u16* __restrict__ t_ni, const u16* __restrict__ t_nj,
    const int* __restrict__ cs_e, const int* __restrict__ cs_src, const int* __restrict__ cs_dst,
    const float* __restrict__ bias_p, const float* __restrict__ attn_p,
    const u16* __restrict__ f_bf, float* __restrict__ out_f, float* __restrict__ part) {
  const int nx = gridDim.x;
  const int nwg = nx * gridDim.y;
  int bid = blockIdx.y * nx + blockIdx.x;
  int q = nwg >> 3, r = nwg & 7;
  int xcd = bid & 7, idx = bid >> 3;
  int wg = (xcd < r) ? (xcd * (q + 1) + idx) : (r * (q + 1) + (xcd - r) * q + idx);
  const int m0 = (wg / nx) * 128;
  const int n0 = (wg % nx) * 128;
  __shared__ __attribute__((aligned(16))) char smem[34816];
  u16* lA = (u16*)smem;
  u16* lB = (u16*)(smem + 16384);
  const int tid = threadIdx.x;
  const int lane = tid & 63;
  const int wid = tid >> 6;
  const int wr = (wid >> 1) * 64;
  const int wc = (wid & 1) * 64;
  const int srow = tid >> 2;
  const int sdst = (tid & 3) * 8;
  const int ssrc = ((tid & 3) ^ ((tid >> 3) & 3)) * 8;
  const int rslot = ((lane >> 4) ^ ((lane >> 1) & 3)) * 8;
  int cse_s[2];
#pragma unroll
  for (int i = 0; i < 2; ++i) cse_s[i] = cs_e[p0 + m0 + srow + i * 64];
  const int rr = lane >> 3;
  const int c0e = (lane & 7) * 8;
  const int j0 = n0 + wc + c0e;
  const int cmod = j0 >> 3;
  const int wgrp = (n0 + wc) >> 6;
  int ep[8];
  u16x8 ni8v[8], nj8v[8];
  u16 fsv[8];
#pragma unroll
  for (int p = 0; p < 8; ++p) {
    int pos = p0 + m0 + wr + p * 8 + rr;
    int e = cs_e[pos];
    int is = cs_src[pos], id = cs_dst[pos];
    ep[p] = e;
    ni8v[p] = *(const u16x8*)(t_ni + (size_t)is * 2048 + j0);
    nj8v[p] = *(const u16x8*)(t_nj + (size_t)id * 2048 + j0);
    fsv[p] = f_bf[(size_t)e * 256 + cmod];
  }
  f32x4 acc[4][4] = {};
#define STAGE(buf, kb)                                                                         \
  {                                                                                            \
    _Pragma("unroll") for (int i = 0; i < 2; ++i) {                                            \
      const int row = srow + i * 64;                                                           \
      __builtin_amdgcn_global_load_lds(                                                        \
          (const __attribute__((address_space(1))) void*)(A + (size_t)cse_s[i] * 256 + (kb) + ssrc), \
          (__attribute__((address_space(3))) void*)(lA + (buf) * 4096 + row * 32 + sdst), 16, 0, 0); \
      __builtin_amdgcn_global_load_lds(                                                        \
          (const __attribute__((address_space(1))) void*)(BT + (size_t)(n0 + row) * 256 + (kb) + ssrc), \
          (__attribute__((address_space(3))) void*)(lB + (buf) * 4096 + row * 32 + sdst), 16, 0, 0); \
    }                                                                                          \
  }
  STAGE(0, 0)
  __syncthreads();
#pragma unroll
  for (int t = 0; t < 8; ++t) {
    if (t < 7) STAGE((t + 1) & 1, (t + 1) * 32)
    const u16* pA = lA + (t & 1) * 4096;
    const u16* pB = lB + (t & 1) * 4096;
    bf16x8 af[4], bfr[4];
#pragma unroll
    for (int m = 0; m < 4; ++m)
      af[m] = *(const bf16x8*)(pA + (wr + m * 16 + (lane & 15)) * 32 + rslot);
#pragma unroll
    for (int n = 0; n < 4; ++n)
      bfr[n] = *(const bf16x8*)(pB + (wc + n * 16 + (lane & 15)) * 32 + rslot);
#pragma unroll
    for (int m = 0; m < 4; ++m)
#pragma unroll
      for (int n = 0; n < 4; ++n)
        acc[m][n] = __builtin_amdgcn_mfma_f32_16x16x32_bf16(af[m], bfr[n], acc[m][n], 0, 0, 0);
    __syncthreads();
  }
#undef STAGE
  const int cr = (lane >> 4) * 4;
  const int cc = lane & 15;
  u16* stg = (u16*)smem + wid * (64 * 68);
#pragma unroll
  for (int m = 0; m < 4; ++m)
#pragma unroll
    for (int n = 0; n < 4; ++n)
#pragma unroll
      for (int j = 0; j < 4; ++j)
        stg[(m * 16 + cr + j) * 68 + n * 16 + cc] = f2bf(acc[m][n][j]);
  f32x4 bias0 = *(const f32x4*)(bias_p + j0);
  f32x4 bias1 = *(const f32x4*)(bias_p + j0 + 4);
  f32x4 attn0 = *(const f32x4*)(attn_p + j0);
  f32x4 attn1 = *(const f32x4*)(attn_p + j0 + 4);
#pragma unroll
  for (int p = 0; p < 8; ++p) {
    int row = p * 8 + rr;
    int er = m0 + wr + row;
    u16x4 w0 = *(const u16x4*)(stg + row * 68 + c0e);
    u16x4 w1 = *(const u16x4*)(stg + row * 68 + c0e + 4);
    float y[8];
#pragma unroll
    for (int h = 0; h < 4; ++h) {
      float t0 = bf2f(w0[h]) + bf2f(ni8v[p][h]) + bf2f(nj8v[p][h]) + bias0[h];
      y[h] = t0 > 0.f ? t0 : 0.01f * t0;
      float t1 = bf2f(w1[h]) + bf2f(ni8v[p][4 + h]) + bf2f(nj8v[p][4 + h]) + bias1[h];
      y[4 + h] = t1 > 0.f ? t1 : 0.01f * t1;
    }
    float outv = 0.125f * (((y[0] + y[1]) + (y[2] + y[3])) + ((y[4] + y[5]) + (y[6] + y[7])));
    out_f[(size_t)ep[p] * 256 + cmod] = outv + bf2f(fsv[p]);
    float lp[8];
#pragma unroll
    for (int h = 0; h < 4; ++h) { lp[h] = y[h] * attn0[h]; lp[4 + h] = y[4 + h] * attn1[h]; }
#pragma unroll
    for (int mask = 1; mask < 8; mask <<= 1)
#pragma unroll
      for (int h = 0; h < 8; ++h) lp[h] += __shfl_xor(lp[h], mask);
    if ((lane & 7) == 0) {
#pragma unroll
      for (int h = 0; h < 8; ++h) part[(size_t)er * 256 + wgrp * 8 + h] = lp[h];
    }
  }
}

// ---- logit partial reduce ----
__global__ __launch_bounds__(256) void logit_reduce(
    int p0, int nech, const float* __restrict__ part, float* __restrict__ exb) {
  int er = blockIdx.x * 4 + (threadIdx.x >> 6);
  if (er >= nech) return;
  int lane = threadIdx.x & 63;
  int h = lane & 7;
  int w0 = (lane >> 3) * 4;
  float s = 0.f;
#pragma unroll
  for (int k = 0; k < 4; ++k) s += part[(size_t)er * 256 + (w0 + k) * 8 + h];
  s += __shfl_xor(s, 8);
  s += __shfl_xor(s, 16);
  s += __shfl_xor(s, 32);
  s = fminf(fmaxf(s, -30.f), 30.f);
  if (lane < 8) exb[(size_t)(p0 + er) * 8 + h] = expf(s);
}

// ---- hidden gather, 1-deep software-pipelined ----
__global__ __launch_bounds__(256) void node_gather_hidden(
    const u16* __restrict__ t3, const int* __restrict__ row_ptr,
    const int* __restrict__ cs_src, const float* __restrict__ exb,
    float* __restrict__ n_cur, u16* __restrict__ n_bf) {
  int node = blockIdx.x * 4 + (threadIdx.x >> 6);
  if (node >= NN) return;
  int lane = threadIdx.x & 63;
  int c = lane * 4, h = lane >> 3;
  int beg = row_ptr[node], end = row_ptr[node + 1];
  float denom = 0.f;
  float acc[4] = {0.f, 0.f, 0.f, 0.f};
  if (beg < end) {
    int s_c = cs_src[beg];
    float a_c = exb[(size_t)beg * 8 + h];
    u16x4 hv_c = *(const u16x4*)(t3 + (size_t)s_c * 768 + 512 + c);
    for (int p = beg; p < end; ++p) {
      int pn = p + 1 < end ? p + 1 : p;
      int s_n = cs_src[pn];
      float a_n = exb[(size_t)pn * 8 + h];
      u16x4 hv_n = *(const u16x4*)(t3 + (size_t)s_n * 768 + 512 + c);
      denom += a_c;
#pragma unroll
      for (int j = 0; j < 4; ++j) acc[j] += a_c * bf2f(hv_c[j]);
      a_c = a_n;
      hv_c = hv_n;
    }
  }
  float inv = denom > 0.f ? 1.f / denom : 0.f;
  size_t i0 = (size_t)node * 256 + c;
  f32x4 nv = *(f32x4*)(n_cur + i0);
  u16x4 bv;
#pragma unroll
  for (int j = 0; j < 4; ++j) {
    float t = acc[j] * inv;
    t = t > 0.f ? t : expm1f(t);
    nv[j] += t;
    bv[j] = f2bf(nv[j]);
  }
  *(f32x4*)(n_cur + i0) = nv;
  *(u16x4*)(n_bf + i0) = bv;
}

// ---- final gather, 1-deep software-pipelined; head-permuted t_node ----
__global__ __launch_bounds__(256) void node_gather_final_all(
    const u16* __restrict__ t_node, const int* __restrict__ row_ptr,
    const int* __restrict__ cs_src, const float* __restrict__ exb,
    const float* __restrict__ n_cur, float* __restrict__ out_n) {
  int node = blockIdx.x * 4 + (threadIdx.x >> 6);
  if (node >= NN) return;
  int lane = threadIdx.x & 63;
  int c = lane * 4;
  int beg = row_ptr[node], end = row_ptr[node + 1];
  float dh[8] = {};
  float acc[8][4] = {};
  if (beg < end) {
    int s_c = cs_src[beg];
    f32x4 a0_c = *(const f32x4*)(exb + (size_t)beg * 8);
    f32x4 a1_c = *(const f32x4*)(exb + (size_t)beg * 8 + 4);
    u16x8 rv_c[4];
    {
      const u16* rowb = t_node + (size_t)s_c * 2048 + (size_t)c * 8;
#pragma unroll
      for (int jj = 0; jj < 4; ++jj) rv_c[jj] = *(const u16x8*)(rowb + jj * 8);
    }
    for (int p = beg; p < end; ++p) {
      int pn = p + 1 < end ? p + 1 : p;
      int s_n = cs_src[pn];
      f32x4 a0_n = *(const f32x4*)(exb + (size_t)pn * 8);
      f32x4 a1_n = *(const f32x4*)(exb + (size_t)pn * 8 + 4);
      u16x8 rv_n[4];
      const u16* rowbn = t_node + (size_t)s_n * 2048 + (size_t)c * 8;
#pragma unroll
      for (int jj = 0; jj < 4; ++jj) rv_n[jj] = *(const u16x8*)(rowbn + jj * 8);
      float a[8] = {a0_c[0], a0_c[1], a0_c[2], a0_c[3], a1_c[0], a1_c[1], a1_c[2], a1_c[3]};
#pragma unroll
      for (int h = 0; h < 8; ++h) {
        dh[h] += a[h];
#pragma unroll
        for (int jj = 0; jj < 4; ++jj) acc[h][jj] += a[h] * bf2f(rv_c[jj][h]);
      }
#pragma unroll
      for (int jj = 0; jj < 4; ++jj) rv_c[jj] = rv_n[jj];
      a0_c = a0_n;
      a1_c = a1_n;
    }
  }
  float total[4] = {0.f, 0.f, 0.f, 0.f};
#pragma unroll
  for (int h = 0; h < 8; ++h) {
    float inv = dh[h] > 0.f ? 0.125f / dh[h] : 0.f;
#pragma unroll
    for (int jj = 0; jj < 4; ++jj) total[jj] += acc[h][jj] * inv;
  }
  size_t i0 = (size_t)node * 256 + c;
  f32x4 nv = *(const f32x4*)(n_cur + i0);
#pragma unroll
  for (int jj = 0; jj < 4; ++jj) nv[jj] += total[jj];
  *(f32x4*)(out_n + i0) = nv;
}

extern "C" void kernel_launch(void* const* d_in, const int* in_sizes, int n_in,
                              void* d_out, int out_size, void* d_ws, size_t ws_size,
                              hipStream_t stream) {
  const float* nfeat   = (const float*)d_in[0];
  const float* efeat   = (const float*)d_in[1];
  const int*   src     = (const int*)d_in[2];
  const int*   dst     = (const int*)d_in[3];
  const float* Wnode_h = (const float*)d_in[4];
  const float* Wni_h   = (const float*)d_in[5];
  const float* Wnj_h   = (const float*)d_in[6];
  const float* Wfij_h  = (const float*)d_in[7];
  const float* attn_h  = (const float*)d_in[8];
  const float* bias_h  = (const float*)d_in[9];
  const float* Wnode_l = (const float*)d_in[10];
  const float* Wni_l   = (const float*)d_in[11];
  const float* Wnj_l   = (const float*)d_in[12];
  const float* Wfij_l  = (const float*)d_in[13];
  const float* attn_l  = (const float*)d_in[14];
  const float* bias_l  = (const float*)d_in[15];

  char* ws = (char*)d_ws;
  size_t off = 0;
  auto alloc = [&](size_t b) { char* p = ws + off; off += (b + 255) & ~(size_t)255; return p; };
  float* n_cur = (float*)alloc((size_t)NN * 256 * 4);
  u16* n_bf    = (u16*)alloc((size_t)NN * 256 * 2);
  u16* f_bf    = (u16*)alloc((size_t)NE * 256 * 2);
  u16* t_ni    = (u16*)alloc((size_t)NN * 2048 * 2);
  u16* t_nj    = (u16*)alloc((size_t)NN * 2048 * 2);
  u16* t_node  = (u16*)alloc((size_t)NN * 2048 * 2);
  float* exb   = (float*)alloc((size_t)NE * 8 * 4);
  u16* WT      = (u16*)alloc((size_t)4 * 65536 * 2);
  u16* WTF     = (u16*)alloc((size_t)4 * 524288 * 2);
  u16* fW      = (u16*)alloc((size_t)NE * 256 * 2);   // f-state ping-pong buffer
  float* biasp = (float*)alloc(2048 * 4);
  float* attnp = (float*)alloc(2048 * 4);
  int* deg     = (int*)alloc((size_t)NN * 4);
  int* cursor  = (int*)alloc((size_t)NN * 4);
  int* row_ptr = (int*)alloc((size_t)(NN + 1) * 4);
  int* cs_e    = (int*)alloc((size_t)NE * 4);
  int* cs_src  = (int*)alloc((size_t)NE * 4);
  int* cs_dst  = (int*)alloc((size_t)NE * 4);
  int ech;
  float* part;
  size_t part_big = (size_t)32000 * 256 * 4;
  if (off + part_big <= ws_size) { ech = 32000; part = (float*)alloc(part_big); }
  else                          { ech = 16000; part = (float*)alloc((size_t)16000 * 256 * 4); }

  u16* WT_fij  = WT + 3 * 65536;
  u16* WTF_node = WTF;
  u16* WTF_ni   = WTF + (size_t)1 * 524288;
  u16* WTF_nj   = WTF + (size_t)2 * 524288;
  u16* WTF_fij  = WTF + (size_t)3 * 524288;

  float* out_n = (float*)d_out;
  float* out_f = out_n + (size_t)NN * 256;

  // CSR build (dst-sorted edge order reused by ALL edge passes)
  hipMemsetAsync(deg, 0, (size_t)NN * 4, stream);
  deg_hist<<<(NE + 255) / 256, 256, 0, stream>>>(dst, deg);
  scan_deg<<<1, 1024, 0, stream>>>(deg, row_ptr, cursor);
  csr_fill<<<(NE + 255) / 256, 256, 0, stream>>>(src, dst, cursor, cs_e, cs_src, cs_dst);

  cast_init<<<1024, 256, 0, stream>>>(nfeat, n_cur, n_bf, NN * 256 / 4);
  cast_bf<<<2048, 256, 0, stream>>>(efeat, f_bf, NE * 256 / 4);

  // hidden layers: node GEMM [NN,768] + FUSED f-GEMM/edge pass (CSR order, ping-pong)
  for (int l = 0; l < 2; ++l) {
    transpose4<<<dim3(16, 16, 4), dim3(16, 16), 0, stream>>>(
        Wni_h + (size_t)l * 65536, Wnj_h + (size_t)l * 65536,
        Wnode_h + (size_t)l * 65536, Wfij_h + (size_t)l * 65536, 256, 65536, WT);
    gemm_abt<<<dim3(6, 125, 1), 256, 0, stream>>>(n_bf, WT, WT, WT,
                                                  t_ni, t_ni, t_ni, 768);
    const u16* fsrc = l == 0 ? f_bf : fW;
    u16* fdst       = l == 0 ? fW : f_bf;
    gemm_fused_hidden<<<dim3(2, 500), 256, 0, stream>>>(
        fsrc, WT_fij, t_ni, cs_e, cs_src, cs_dst,
        bias_h + (size_t)l * 256, attn_h + (size_t)l * 256, fdst, exb);
    node_gather_hidden<<<4000, 256, 0, stream>>>(t_ni, row_ptr, cs_src, exb, n_cur, n_bf);
  }

  // final layer: head-permuted weights/tables; fused f-GEMM in CSR order
  transpose4p<<<dim3(128, 16, 4), dim3(16, 16), 0, stream>>>(
      Wnode_l, Wni_l, Wnj_l, Wfij_l, WTF);
  permute_ba<<<8, 256, 0, stream>>>(bias_l, attn_l, biasp, attnp);
  gemm_abt<<<dim3(16, 125, 3), 256, 0, stream>>>(n_bf, WTF_ni, WTF_nj, WTF_node,
                                                 t_ni, t_nj, t_node, 2048);
  for (int p0 = 0; p0 < NE; p0 += ech) {
    gemm_fused_final<<<dim3(16, ech / 128), 256, 0, stream>>>(
        p0, f_bf, WTF_fij, t_ni, t_nj, cs_e, cs_src, cs_dst,
        biasp, attnp, f_bf, out_f, part);
    logit_reduce<<<ech / 4, 256, 0, stream>>>(p0, ech, part, exb);
  }
  node_gather_final_all<<<4000, 256, 0, stream>>>(t_node, row_ptr, cs_src,
                                                  exb, n_cur, out_n);
}

// Round 18
// 592.838 us; speedup vs baseline: 1.0530x; 1.0530x over previous
//
#include <hip/hip_runtime.h>

typedef unsigned short u16;
typedef __attribute__((ext_vector_type(4))) unsigned short u16x4;
typedef __attribute__((ext_vector_type(8))) unsigned short u16x8;
typedef __attribute__((ext_vector_type(4))) float f32x4;
typedef __attribute__((ext_vector_type(8))) __bf16 bf16x8;

#define NN 16000
#define NE 64000

__device__ __forceinline__ float bf2f(u16 b) {
  union { unsigned int u; float f; } v; v.u = ((unsigned int)b) << 16; return v.f;
}
__device__ __forceinline__ u16 f2bf(float x) {
  union { float f; unsigned int u; } v; v.f = x;
  unsigned int r = v.u + 0x7FFFu + ((v.u >> 16) & 1u);
  return (u16)(r >> 16);
}

// ---------------- node init: f32 working copy + bf16 mirror ----------------
__global__ void cast_init(const float* __restrict__ in, float* __restrict__ outf,
                          u16* __restrict__ outb, int n4) {
  for (int i = blockIdx.x * blockDim.x + threadIdx.x; i < n4; i += gridDim.x * blockDim.x) {
    f32x4 v = ((const f32x4*)in)[i];
    u16x4 b;
#pragma unroll
    for (int j = 0; j < 4; ++j) b[j] = f2bf(v[j]);
    ((f32x4*)outf)[i] = v;
    ((u16x4*)outb)[i] = b;
  }
}

// ---------------- edge init: bf16 state only ----------------
__global__ void cast_bf(const float* __restrict__ in, u16* __restrict__ outb, int n4) {
  for (int i = blockIdx.x * blockDim.x + threadIdx.x; i < n4; i += gridDim.x * blockDim.x) {
    f32x4 v = ((const f32x4*)in)[i];
    u16x4 b;
#pragma unroll
    for (int j = 0; j < 4; ++j) b[j] = f2bf(v[j]);
    ((u16x4*)outb)[i] = b;
  }
}

// ---------------- CSR build ----------------
__global__ void deg_hist(const int* __restrict__ dst, int* __restrict__ deg) {
  int e = blockIdx.x * 256 + threadIdx.x;
  if (e < NE) atomicAdd(&deg[dst[e]], 1);
}

__global__ __launch_bounds__(1024) void scan_deg(const int* __restrict__ deg,
                                                 int* __restrict__ row_ptr,
                                                 int* __restrict__ cursor) {
  __shared__ int lds[1024];
  int t = threadIdx.x;
  int base = t * 16;
  int v[16];
  int s = 0;
#pragma unroll
  for (int j = 0; j < 16; ++j) {
    int idx = base + j;
    v[j] = idx < NN ? deg[idx] : 0;
    s += v[j];
  }
  lds[t] = s;
  __syncthreads();
  for (int d = 1; d < 1024; d <<= 1) {
    int x = t >= d ? lds[t - d] : 0;
    __syncthreads();
    lds[t] += x;
    __syncthreads();
  }
  int run = lds[t] - s;
  for (int j = 0; j < 16; ++j) {
    int idx = base + j;
    if (idx < NN) { row_ptr[idx] = run; cursor[idx] = run; run += v[j]; }
  }
  if (t == 1023) row_ptr[NN] = run;
}

__global__ void csr_fill(const int* __restrict__ src, const int* __restrict__ dst,
                         int* __restrict__ cursor, int* __restrict__ cs_e,
                         int* __restrict__ cs_src, int* __restrict__ cs_dst) {
  int e = blockIdx.x * 256 + threadIdx.x;
  if (e >= NE) return;
  int d = dst[e];
  int pos = atomicAdd(&cursor[d], 1);
  cs_e[pos] = e;
  cs_src[pos] = src[e];
  cs_dst[pos] = d;
}

// ---- weight transpose + bf16 cast: WT[z*osz + n*256 + k] = bf16(W[k][n]) ----
__global__ void transpose4(const float* __restrict__ W0, const float* __restrict__ W1,
                           const float* __restrict__ W2, const float* __restrict__ W3,
                           int ld, int osz, u16* __restrict__ WT) {
  __shared__ float t[16][17];
  int z = blockIdx.z;
  const float* W = z == 0 ? W0 : (z == 1 ? W1 : (z == 2 ? W2 : W3));
  u16* O = WT + (size_t)z * osz;
  int n0 = blockIdx.x * 16, k0 = blockIdx.y * 16;
  int tx = threadIdx.x, ty = threadIdx.y;
  t[ty][tx] = W[(size_t)(k0 + ty) * ld + n0 + tx];
  __syncthreads();
  O[(size_t)(n0 + ty) * 256 + k0 + tx] = f2bf(t[tx][ty]);
}

// ---- final-weight transpose with head-interleave: col n=h*256+c -> j=c*8+h ----
__global__ void transpose4p(const float* __restrict__ W0, const float* __restrict__ W1,
                            const float* __restrict__ W2, const float* __restrict__ W3,
                            u16* __restrict__ WT) {
  __shared__ float t[16][17];
  int z = blockIdx.z;
  const float* W = z == 0 ? W0 : (z == 1 ? W1 : (z == 2 ? W2 : W3));
  u16* O = WT + (size_t)z * 524288;
  int n0 = blockIdx.x * 16, k0 = blockIdx.y * 16;
  int tx = threadIdx.x, ty = threadIdx.y;
  t[ty][tx] = W[(size_t)(k0 + ty) * 2048 + n0 + tx];
  __syncthreads();
  int n = n0 + ty;
  int j = (n & 255) * 8 + (n >> 8);
  O[(size_t)j * 256 + k0 + tx] = f2bf(t[tx][ty]);
}

// ---- bias/attn head-interleave permute ----
__global__ void permute_ba(const float* __restrict__ bias, const float* __restrict__ attn,
                           float* __restrict__ bias_p, float* __restrict__ attn_p) {
  int n = blockIdx.x * 256 + threadIdx.x;
  int j = (n & 255) * 8 + (n >> 8);
  bias_p[j] = bias[n];
  attn_p[j] = attn[n];
}

// ------------- bf16 GEMM (r9 proven form): 2-phase BK=64, T2 LDS swizzle, T1 XCD swizzle,
// ------------- LDS-staged coalesced C-write -------------
__global__ __launch_bounds__(256) void gemm_abt(
    const u16* __restrict__ A,
    const u16* __restrict__ BT0, const u16* __restrict__ BT1, const u16* __restrict__ BT2,
    u16* __restrict__ C0, u16* __restrict__ C1, u16* __restrict__ C2, int ldc) {
  const int bz = blockIdx.z;
  const u16* BT = bz == 0 ? BT0 : (bz == 1 ? BT1 : BT2);
  u16* C = bz == 0 ? C0 : (bz == 1 ? C1 : C2);
  const int nx = gridDim.x;
  const int nwg = nx * gridDim.y;
  int bid = blockIdx.y * nx + blockIdx.x;
  int q = nwg >> 3, r = nwg & 7;
  int xcd = bid & 7, idx = bid >> 3;
  int wg = (xcd < r) ? (xcd * (q + 1) + idx) : (r * (q + 1) + (xcd - r) * q + idx);
  const int m0 = (wg / nx) * 128;
  const int n0 = (wg % nx) * 128;
  __shared__ __attribute__((aligned(16))) char smem[69632];
  u16* lA = (u16*)smem;
  u16* lB = (u16*)(smem + 32768);
  const int tid = threadIdx.x;
  const int lane = tid & 63;
  const int wid = tid >> 6;
  const int wr = (wid >> 1) * 64;
  const int wc = (wid & 1) * 64;
  const int srow = tid >> 3;
  const int sdst = (tid & 7) * 8;
  const int ssrc = (((tid & 7) ^ (srow & 7))) * 8;
  const int sx = (lane >> 4) ^ (lane & 7);
  f32x4 acc[4][4] = {};
#define STAGE(buf, kb)                                                                         \
  {                                                                                            \
    _Pragma("unroll") for (int i = 0; i < 4; ++i) {                                            \
      const int row = srow + i * 32;                                                           \
      __builtin_amdgcn_global_load_lds(                                                        \
          (const __attribute__((address_space(1))) void*)(A + (size_t)(m0 + row) * 256 + (kb) + ssrc), \
          (__attribute__((address_space(3))) void*)(lA + (buf) * 8192 + row * 64 + sdst), 16, 0, 0); \
      __builtin_amdgcn_global_load_lds(                                                        \
          (const __attribute__((address_space(1))) void*)(BT + (size_t)(n0 + row) * 256 + (kb) + ssrc), \
          (__attribute__((address_space(3))) void*)(lB + (buf) * 8192 + row * 64 + sdst), 16, 0, 0); \
    }                                                                                          \
  }
  STAGE(0, 0)
  __syncthreads();
#pragma unroll
  for (int t = 0; t < 4; ++t) {
    if (t < 3) STAGE((t + 1) & 1, (t + 1) * 64)
    const u16* pA = lA + (t & 1) * 8192;
    const u16* pB = lB + (t & 1) * 8192;
#pragma unroll
    for (int kk = 0; kk < 2; ++kk) {
      const int sw = ((kk << 2) ^ sx) * 8;
      bf16x8 af[4], bfr[4];
#pragma unroll
      for (int m = 0; m < 4; ++m)
        af[m] = *(const bf16x8*)(pA + (wr + m * 16 + (lane & 15)) * 64 + sw);
#pragma unroll
      for (int n = 0; n < 4; ++n)
        bfr[n] = *(const bf16x8*)(pB + (wc + n * 16 + (lane & 15)) * 64 + sw);
#pragma unroll
      for (int m = 0; m < 4; ++m)
#pragma unroll
        for (int n = 0; n < 4; ++n)
          acc[m][n] = __builtin_amdgcn_mfma_f32_16x16x32_bf16(af[m], bfr[n], acc[m][n], 0, 0, 0);
    }
    __syncthreads();
  }
#undef STAGE
  const int cr = (lane >> 4) * 4;
  const int cc = lane & 15;
  float* stg = (float*)smem + wid * (64 * 68);
#pragma unroll
  for (int m = 0; m < 4; ++m)
#pragma unroll
    for (int n = 0; n < 4; ++n)
#pragma unroll
      for (int j = 0; j < 4; ++j)
        stg[(m * 16 + cr + j) * 68 + n * 16 + cc] = acc[m][n][j];
  const int rr = lane >> 3;
  const int c0 = (lane & 7) * 8;
#pragma unroll
  for (int p = 0; p < 8; ++p) {
    int row = p * 8 + rr;
    f32x4 v0 = *(const f32x4*)(stg + row * 68 + c0);
    f32x4 v1 = *(const f32x4*)(stg + row * 68 + c0 + 4);
    u16x8 o;
#pragma unroll
    for (int i = 0; i < 4; ++i) { o[i] = f2bf(v0[i]); o[4 + i] = f2bf(v1[i]); }
    *(u16x8*)(&C[(size_t)(m0 + wr + row) * ldc + (n0 + wc + c0)]) = o;
  }
}

// ------------- FUSED hidden f-GEMM, CSR-ordered edges (r16 proven form) -------------
__global__ __launch_bounds__(256) void gemm_fused_hidden(
    const u16* __restrict__ A, const u16* __restrict__ BT, const u16* __restrict__ t3,
    const int* __restrict__ cs_e, const int* __restrict__ cs_src, const int* __restrict__ cs_dst,
    const float* __restrict__ bias, const float* __restrict__ attn,
    u16* __restrict__ f_new, float* __restrict__ exb) {
  const int nx = gridDim.x;
  const int nwg = nx * gridDim.y;
  int bid = blockIdx.y * nx + blockIdx.x;
  int q = nwg >> 3, r = nwg & 7;
  int xcd = bid & 7, idx = bid >> 3;
  int wg = (xcd < r) ? (xcd * (q + 1) + idx) : (r * (q + 1) + (xcd - r) * q + idx);
  const int m0 = (wg / nx) * 128;
  const int n0 = (wg % nx) * 128;
  __shared__ __attribute__((aligned(16))) char smem[69632];
  u16* lA = (u16*)smem;
  u16* lB = (u16*)(smem + 32768);
  const int tid = threadIdx.x;
  const int lane = tid & 63;
  const int wid = tid >> 6;
  const int wr = (wid >> 1) * 64;
  const int wc = (wid & 1) * 64;
  const int srow = tid >> 3;
  const int sdst = (tid & 7) * 8;
  const int ssrc = (((tid & 7) ^ (srow & 7))) * 8;
  const int sx = (lane >> 4) ^ (lane & 7);
  int cse_s[4];
#pragma unroll
  for (int i = 0; i < 4; ++i) cse_s[i] = cs_e[m0 + srow + i * 32];
  const int rr = lane >> 3;
  const int c0e = (lane & 7) * 8;
  const int j0 = n0 + wc + c0e;
  const int head = j0 >> 5;
  int ep[8];
  u16x8 va8[8], vb8[8], fs8[8];
#pragma unroll
  for (int p = 0; p < 8; ++p) {
    int pos = m0 + wr + p * 8 + rr;
    int e = cs_e[pos];
    int is = cs_src[pos], id = cs_dst[pos];
    ep[p] = e;
    va8[p] = *(const u16x8*)(t3 + (size_t)is * 768 + j0);
    vb8[p] = *(const u16x8*)(t3 + (size_t)id * 768 + 256 + j0);
    fs8[p] = *(const u16x8*)(A + (size_t)e * 256 + j0);
  }
  f32x4 acc[4][4] = {};
#define STAGE(buf, kb)                                                                         \
  {                                                                                            \
    _Pragma("unroll") for (int i = 0; i < 4; ++i) {                                            \
      const int row = srow + i * 32;                                                           \
      __builtin_amdgcn_global_load_lds(                                                        \
          (const __attribute__((address_space(1))) void*)(A + (size_t)cse_s[i] * 256 + (kb) + ssrc), \
          (__attribute__((address_space(3))) void*)(lA + (buf) * 8192 + row * 64 + sdst), 16, 0, 0); \
      __builtin_amdgcn_global_load_lds(                                                        \
          (const __attribute__((address_space(1))) void*)(BT + (size_t)(n0 + row) * 256 + (kb) + ssrc), \
          (__attribute__((address_space(3))) void*)(lB + (buf) * 8192 + row * 64 + sdst), 16, 0, 0); \
    }                                                                                          \
  }
  STAGE(0, 0)
  __syncthreads();
#pragma unroll
  for (int t = 0; t < 4; ++t) {
    if (t < 3) STAGE((t + 1) & 1, (t + 1) * 64)
    const u16* pA = lA + (t & 1) * 8192;
    const u16* pB = lB + (t & 1) * 8192;
#pragma unroll
    for (int kk = 0; kk < 2; ++kk) {
      const int sw = ((kk << 2) ^ sx) * 8;
      bf16x8 af[4], bfr[4];
#pragma unroll
      for (int m = 0; m < 4; ++m)
        af[m] = *(const bf16x8*)(pA + (wr + m * 16 + (lane & 15)) * 64 + sw);
#pragma unroll
      for (int n = 0; n < 4; ++n)
        bfr[n] = *(const bf16x8*)(pB + (wc + n * 16 + (lane & 15)) * 64 + sw);
#pragma unroll
      for (int m = 0; m < 4; ++m)
#pragma unroll
        for (int n = 0; n < 4; ++n)
          acc[m][n] = __builtin_amdgcn_mfma_f32_16x16x32_bf16(af[m], bfr[n], acc[m][n], 0, 0, 0);
    }
    __syncthreads();
  }
#undef STAGE
  const int cr = (lane >> 4) * 4;
  const int cc = lane & 15;
  float* stg = (float*)smem + wid * (64 * 68);
#pragma unroll
  for (int m = 0; m < 4; ++m)
#pragma unroll
    for (int n = 0; n < 4; ++n)
#pragma unroll
      for (int j = 0; j < 4; ++j)
        stg[(m * 16 + cr + j) * 68 + n * 16 + cc] = acc[m][n][j];
  f32x4 bias0 = *(const f32x4*)(bias + j0);
  f32x4 bias1 = *(const f32x4*)(bias + j0 + 4);
  f32x4 attn0 = *(const f32x4*)(attn + j0);
  f32x4 attn1 = *(const f32x4*)(attn + j0 + 4);
#pragma unroll
  for (int p = 0; p < 8; ++p) {
    int row = p * 8 + rr;
    int pos = m0 + wr + row;
    f32x4 v0 = *(const f32x4*)(stg + row * 68 + c0e);
    f32x4 v1 = *(const f32x4*)(stg + row * 68 + c0e + 4);
    float lp = 0.f;
    u16x8 o;
#pragma unroll
    for (int h = 0; h < 4; ++h) {
      float t0 = v0[h] + bf2f(va8[p][h]) + bf2f(vb8[p][h]) + bias0[h];
      t0 = t0 > 0.f ? t0 : 0.01f * t0;
      lp += t0 * attn0[h];
      float e0 = t0 > 0.f ? t0 : expm1f(t0);
      o[h] = f2bf(bf2f(fs8[p][h]) + e0);
      float t1 = v1[h] + bf2f(va8[p][4 + h]) + bf2f(vb8[p][4 + h]) + bias1[h];
      t1 = t1 > 0.f ? t1 : 0.01f * t1;
      lp += t1 * attn1[h];
      float e1 = t1 > 0.f ? t1 : expm1f(t1);
      o[4 + h] = f2bf(bf2f(fs8[p][4 + h]) + e1);
    }
    *(u16x8*)(&f_new[(size_t)ep[p] * 256 + j0]) = o;
    lp += __shfl_xor(lp, 1);
    lp += __shfl_xor(lp, 2);
    lp = fminf(fmaxf(lp, -30.f), 30.f);
    if ((lane & 3) == 0) exb[(size_t)pos * 8 + head] = expf(lp);
  }
}

// ------------- FUSED final f-GEMM, CSR-ordered edges, prologue-prefetched (r16 form) -------------
__global__ __launch_bounds__(256) void gemm_fused_final(
    int p0, const u16* __restrict__ A, const u16* __restrict__ BT,
    const u16* __restrict__ t_ni, const u16* __restrict__ t_nj,
    const int* __restrict__ cs_e, const int* __restrict__ cs_src, const int* __restrict__ cs_dst,
    const float* __restrict__ bias_p, const float* __restrict__ attn_p,
    const u16* __restrict__ f_bf, float* __restrict__ out_f, float* __restrict__ part) {
  const int nx = gridDim.x;
  const int nwg = nx * gridDim.y;
  int bid = blockIdx.y * nx + blockIdx.x;
  int q = nwg >> 3, r = nwg & 7;
  int xcd = bid & 7, idx = bid >> 3;
  int wg = (xcd < r) ? (xcd * (q + 1) + idx) : (r * (q + 1) + (xcd - r) * q + idx);
  const int m0 = (wg / nx) * 128;
  const int n0 = (wg % nx) * 128;
  __shared__ __attribute__((aligned(16))) char smem[69632];
  u16* lA = (u16*)smem;
  u16* lB = (u16*)(smem + 32768);
  const int tid = threadIdx.x;
  const int lane = tid & 63;
  const int wid = tid >> 6;
  const int wr = (wid >> 1) * 64;
  const int wc = (wid & 1) * 64;
  const int srow = tid >> 3;
  const int sdst = (tid & 7) * 8;
  const int ssrc = (((tid & 7) ^ (srow & 7))) * 8;
  const int sx = (lane >> 4) ^ (lane & 7);
  int cse_s[4];
#pragma unroll
  for (int i = 0; i < 4; ++i) cse_s[i] = cs_e[p0 + m0 + srow + i * 32];
  const int rr = lane >> 3;
  const int c0e = (lane & 7) * 8;
  const int j0 = n0 + wc + c0e;
  const int cmod = j0 >> 3;
  const int wgrp = (n0 + wc) >> 6;
  int ep[8];
  u16x8 ni8v[8], nj8v[8];
  u16 fsv[8];
#pragma unroll
  for (int p = 0; p < 8; ++p) {
    int pos = p0 + m0 + wr + p * 8 + rr;
    int e = cs_e[pos];
    int is = cs_src[pos], id = cs_dst[pos];
    ep[p] = e;
    ni8v[p] = *(const u16x8*)(t_ni + (size_t)is * 2048 + j0);
    nj8v[p] = *(const u16x8*)(t_nj + (size_t)id * 2048 + j0);
    fsv[p] = f_bf[(size_t)e * 256 + cmod];
  }
  f32x4 acc[4][4] = {};
#define STAGE(buf, kb)                                                                         \
  {                                                                                            \
    _Pragma("unroll") for (int i = 0; i < 4; ++i) {                                            \
      const int row = srow + i * 32;                                                           \
      __builtin_amdgcn_global_load_lds(                                                        \
          (const __attribute__((address_space(1))) void*)(A + (size_t)cse_s[i] * 256 + (kb) + ssrc), \
          (__attribute__((address_space(3))) void*)(lA + (buf) * 8192 + row * 64 + sdst), 16, 0, 0); \
      __builtin_amdgcn_global_load_lds(                                                        \
          (const __attribute__((address_space(1))) void*)(BT + (size_t)(n0 + row) * 256 + (kb) + ssrc), \
          (__attribute__((address_space(3))) void*)(lB + (buf) * 8192 + row * 64 + sdst), 16, 0, 0); \
    }                                                                                          \
  }
  STAGE(0, 0)
  __syncthreads();
#pragma unroll
  for (int t = 0; t < 4; ++t) {
    if (t < 3) STAGE((t + 1) & 1, (t + 1) * 64)
    const u16* pA = lA + (t & 1) * 8192;
    const u16* pB = lB + (t & 1) * 8192;
#pragma unroll
    for (int kk = 0; kk < 2; ++kk) {
      const int sw = ((kk << 2) ^ sx) * 8;
      bf16x8 af[4], bfr[4];
#pragma unroll
      for (int m = 0; m < 4; ++m)
        af[m] = *(const bf16x8*)(pA + (wr + m * 16 + (lane & 15)) * 64 + sw);
#pragma unroll
      for (int n = 0; n < 4; ++n)
        bfr[n] = *(const bf16x8*)(pB + (wc + n * 16 + (lane & 15)) * 64 + sw);
#pragma unroll
      for (int m = 0; m < 4; ++m)
#pragma unroll
        for (int n = 0; n < 4; ++n)
          acc[m][n] = __builtin_amdgcn_mfma_f32_16x16x32_bf16(af[m], bfr[n], acc[m][n], 0, 0, 0);
    }
    __syncthreads();
  }
#undef STAGE
  const int cr = (lane >> 4) * 4;
  const int cc = lane & 15;
  float* stg = (float*)smem + wid * (64 * 68);
#pragma unroll
  for (int m = 0; m < 4; ++m)
#pragma unroll
    for (int n = 0; n < 4; ++n)
#pragma unroll
      for (int j = 0; j < 4; ++j)
        stg[(m * 16 + cr + j) * 68 + n * 16 + cc] = acc[m][n][j];
  f32x4 bias0 = *(const f32x4*)(bias_p + j0);
  f32x4 bias1 = *(const f32x4*)(bias_p + j0 + 4);
  f32x4 attn0 = *(const f32x4*)(attn_p + j0);
  f32x4 attn1 = *(const f32x4*)(attn_p + j0 + 4);
#pragma unroll
  for (int p = 0; p < 8; ++p) {
    int row = p * 8 + rr;
    int er = m0 + wr + row;
    f32x4 v0 = *(const f32x4*)(stg + row * 68 + c0e);
    f32x4 v1 = *(const f32x4*)(stg + row * 68 + c0e + 4);
    float y[8];
#pragma unroll
    for (int h = 0; h < 4; ++h) {
      float t0 = v0[h] + bf2f(ni8v[p][h]) + bf2f(nj8v[p][h]) + bias0[h];
      y[h] = t0 > 0.f ? t0 : 0.01f * t0;
      float t1 = v1[h] + bf2f(ni8v[p][4 + h]) + bf2f(nj8v[p][4 + h]) + bias1[h];
      y[4 + h] = t1 > 0.f ? t1 : 0.01f * t1;
    }
    float outv = 0.125f * (((y[0] + y[1]) + (y[2] + y[3])) + ((y[4] + y[5]) + (y[6] + y[7])));
    out_f[(size_t)ep[p] * 256 + cmod] = outv + bf2f(fsv[p]);
    float lp[8];
#pragma unroll
    for (int h = 0; h < 4; ++h) { lp[h] = y[h] * attn0[h]; lp[4 + h] = y[4 + h] * attn1[h]; }
#pragma unroll
    for (int mask = 1; mask < 8; mask <<= 1)
#pragma unroll
      for (int h = 0; h < 8; ++h) lp[h] += __shfl_xor(lp[h], mask);
    if ((lane & 7) == 0) {
#pragma unroll
      for (int h = 0; h < 8; ++h) part[(size_t)er * 256 + wgrp * 8 + h] = lp[h];
    }
  }
}

// ---- logit partial reduce ----
__global__ __launch_bounds__(256) void logit_reduce(
    int p0, int nech, const float* __restrict__ part, float* __restrict__ exb) {
  int er = blockIdx.x * 4 + (threadIdx.x >> 6);
  if (er >= nech) return;
  int lane = threadIdx.x & 63;
  int h = lane & 7;
  int w0 = (lane >> 3) * 4;
  float s = 0.f;
#pragma unroll
  for (int k = 0; k < 4; ++k) s += part[(size_t)er * 256 + (w0 + k) * 8 + h];
  s += __shfl_xor(s, 8);
  s += __shfl_xor(s, 16);
  s += __shfl_xor(s, 32);
  s = fminf(fmaxf(s, -30.f), 30.f);
  if (lane < 8) exb[(size_t)(p0 + er) * 8 + h] = expf(s);
}

// ---- hidden gather, 1-deep software-pipelined ----
__global__ __launch_bounds__(256) void node_gather_hidden(
    const u16* __restrict__ t3, const int* __restrict__ row_ptr,
    const int* __restrict__ cs_src, const float* __restrict__ exb,
    float* __restrict__ n_cur, u16* __restrict__ n_bf) {
  int node = blockIdx.x * 4 + (threadIdx.x >> 6);
  if (node >= NN) return;
  int lane = threadIdx.x & 63;
  int c = lane * 4, h = lane >> 3;
  int beg = row_ptr[node], end = row_ptr[node + 1];
  float denom = 0.f;
  float acc[4] = {0.f, 0.f, 0.f, 0.f};
  if (beg < end) {
    int s_c = cs_src[beg];
    float a_c = exb[(size_t)beg * 8 + h];
    u16x4 hv_c = *(const u16x4*)(t3 + (size_t)s_c * 768 + 512 + c);
    for (int p = beg; p < end; ++p) {
      int pn = p + 1 < end ? p + 1 : p;
      int s_n = cs_src[pn];
      float a_n = exb[(size_t)pn * 8 + h];
      u16x4 hv_n = *(const u16x4*)(t3 + (size_t)s_n * 768 + 512 + c);
      denom += a_c;
#pragma unroll
      for (int j = 0; j < 4; ++j) acc[j] += a_c * bf2f(hv_c[j]);
      a_c = a_n;
      hv_c = hv_n;
    }
  }
  float inv = denom > 0.f ? 1.f / denom : 0.f;
  size_t i0 = (size_t)node * 256 + c;
  f32x4 nv = *(f32x4*)(n_cur + i0);
  u16x4 bv;
#pragma unroll
  for (int j = 0; j < 4; ++j) {
    float t = acc[j] * inv;
    t = t > 0.f ? t : expm1f(t);
    nv[j] += t;
    bv[j] = f2bf(nv[j]);
  }
  *(f32x4*)(n_cur + i0) = nv;
  *(u16x4*)(n_bf + i0) = bv;
}

// ---- final gather, 1-deep software-pipelined; head-permuted t_node ----
__global__ __launch_bounds__(256) void node_gather_final_all(
    const u16* __restrict__ t_node, const int* __restrict__ row_ptr,
    const int* __restrict__ cs_src, const float* __restrict__ exb,
    const float* __restrict__ n_cur, float* __restrict__ out_n) {
  int node = blockIdx.x * 4 + (threadIdx.x >> 6);
  if (node >= NN) return;
  int lane = threadIdx.x & 63;
  int c = lane * 4;
  int beg = row_ptr[node], end = row_ptr[node + 1];
  float dh[8] = {};
  float acc[8][4] = {};
  if (beg < end) {
    int s_c = cs_src[beg];
    f32x4 a0_c = *(const f32x4*)(exb + (size_t)beg * 8);
    f32x4 a1_c = *(const f32x4*)(exb + (size_t)beg * 8 + 4);
    u16x8 rv_c[4];
    {
      const u16* rowb = t_node + (size_t)s_c * 2048 + (size_t)c * 8;
#pragma unroll
      for (int jj = 0; jj < 4; ++jj) rv_c[jj] = *(const u16x8*)(rowb + jj * 8);
    }
    for (int p = beg; p < end; ++p) {
      int pn = p + 1 < end ? p + 1 : p;
      int s_n = cs_src[pn];
      f32x4 a0_n = *(const f32x4*)(exb + (size_t)pn * 8);
      f32x4 a1_n = *(const f32x4*)(exb + (size_t)pn * 8 + 4);
      u16x8 rv_n[4];
      const u16* rowbn = t_node + (size_t)s_n * 2048 + (size_t)c * 8;
#pragma unroll
      for (int jj = 0; jj < 4; ++jj) rv_n[jj] = *(const u16x8*)(rowbn + jj * 8);
      float a[8] = {a0_c[0], a0_c[1], a0_c[2], a0_c[3], a1_c[0], a1_c[1], a1_c[2], a1_c[3]};
#pragma unroll
      for (int h = 0; h < 8; ++h) {
        dh[h] += a[h];
#pragma unroll
        for (int jj = 0; jj < 4; ++jj) acc[h][jj] += a[h] * bf2f(rv_c[jj][h]);
      }
#pragma unroll
      for (int jj = 0; jj < 4; ++jj) rv_c[jj] = rv_n[jj];
      a0_c = a0_n;
      a1_c = a1_n;
    }
  }
  float total[4] = {0.f, 0.f, 0.f, 0.f};
#pragma unroll
  for (int h = 0; h < 8; ++h) {
    float inv = dh[h] > 0.f ? 0.125f / dh[h] : 0.f;
#pragma unroll
    for (int jj = 0; jj < 4; ++jj) total[jj] += acc[h][jj] * inv;
  }
  size_t i0 = (size_t)node * 256 + c;
  f32x4 nv = *(const f32x4*)(n_cur + i0);
#pragma unroll
  for (int jj = 0; jj < 4; ++jj) nv[jj] += total[jj];
  *(f32x4*)(out_n + i0) = nv;
}

extern "C" void kernel_launch(void* const* d_in, const int* in_sizes, int n_in,
                              void* d_out, int out_size, void* d_ws, size_t ws_size,
                              hipStream_t stream) {
  const float* nfeat   = (const float*)d_in[0];
  const float* efeat   = (const float*)d_in[1];
  const int*   src     = (const int*)d_in[2];
  const int*   dst     = (const int*)d_in[3];
  const float* Wnode_h = (const float*)d_in[4];
  const float* Wni_h   = (const float*)d_in[5];
  const float* Wnj_h   = (const float*)d_in[6];
  const float* Wfij_h  = (const float*)d_in[7];
  const float* attn_h  = (const float*)d_in[8];
  const float* bias_h  = (const float*)d_in[9];
  const float* Wnode_l = (const float*)d_in[10];
  const float* Wni_l   = (const float*)d_in[11];
  const float* Wnj_l   = (const float*)d_in[12];
  const float* Wfij_l  = (const float*)d_in[13];
  const float* attn_l  = (const float*)d_in[14];
  const float* bias_l  = (const float*)d_in[15];

  char* ws = (char*)d_ws;
  size_t off = 0;
  auto alloc = [&](size_t b) { char* p = ws + off; off += (b + 255) & ~(size_t)255; return p; };
  float* n_cur = (float*)alloc((size_t)NN * 256 * 4);
  u16* n_bf    = (u16*)alloc((size_t)NN * 256 * 2);
  u16* f_bf    = (u16*)alloc((size_t)NE * 256 * 2);
  u16* t_ni    = (u16*)alloc((size_t)NN * 2048 * 2);
  u16* t_nj    = (u16*)alloc((size_t)NN * 2048 * 2);
  u16* t_node  = (u16*)alloc((size_t)NN * 2048 * 2);
  float* exb   = (float*)alloc((size_t)NE * 8 * 4);
  u16* WT      = (u16*)alloc((size_t)4 * 65536 * 2);
  u16* WTF     = (u16*)alloc((size_t)4 * 524288 * 2);
  u16* fW      = (u16*)alloc((size_t)NE * 256 * 2);   // f-state ping-pong buffer
  float* biasp = (float*)alloc(2048 * 4);
  float* attnp = (float*)alloc(2048 * 4);
  int* deg     = (int*)alloc((size_t)NN * 4);
  int* cursor  = (int*)alloc((size_t)NN * 4);
  int* row_ptr = (int*)alloc((size_t)(NN + 1) * 4);
  int* cs_e    = (int*)alloc((size_t)NE * 4);
  int* cs_src  = (int*)alloc((size_t)NE * 4);
  int* cs_dst  = (int*)alloc((size_t)NE * 4);
  int ech;
  float* part;
  size_t part_big = (size_t)32000 * 256 * 4;
  if (off + part_big <= ws_size) { ech = 32000; part = (float*)alloc(part_big); }
  else                          { ech = 16000; part = (float*)alloc((size_t)16000 * 256 * 4); }

  u16* WT_fij  = WT + 3 * 65536;
  u16* WTF_node = WTF;
  u16* WTF_ni   = WTF + (size_t)1 * 524288;
  u16* WTF_nj   = WTF + (size_t)2 * 524288;
  u16* WTF_fij  = WTF + (size_t)3 * 524288;

  float* out_n = (float*)d_out;
  float* out_f = out_n + (size_t)NN * 256;

  // CSR build (dst-sorted edge order reused by ALL edge passes)
  hipMemsetAsync(deg, 0, (size_t)NN * 4, stream);
  deg_hist<<<(NE + 255) / 256, 256, 0, stream>>>(dst, deg);
  scan_deg<<<1, 1024, 0, stream>>>(deg, row_ptr, cursor);
  csr_fill<<<(NE + 255) / 256, 256, 0, stream>>>(src, dst, cursor, cs_e, cs_src, cs_dst);

  cast_init<<<1024, 256, 0, stream>>>(nfeat, n_cur, n_bf, NN * 256 / 4);
  cast_bf<<<2048, 256, 0, stream>>>(efeat, f_bf, NE * 256 / 4);

  // hidden layers: node GEMM [NN,768] + FUSED f-GEMM/edge pass (CSR order, ping-pong)
  for (int l = 0; l < 2; ++l) {
    transpose4<<<dim3(16, 16, 4), dim3(16, 16), 0, stream>>>(
        Wni_h + (size_t)l * 65536, Wnj_h + (size_t)l * 65536,
        Wnode_h + (size_t)l * 65536, Wfij_h + (size_t)l * 65536, 256, 65536, WT);
    gemm_abt<<<dim3(6, 125, 1), 256, 0, stream>>>(n_bf, WT, WT, WT,
                                                  t_ni, t_ni, t_ni, 768);
    const u16* fsrc = l == 0 ? f_bf : fW;
    u16* fdst       = l == 0 ? fW : f_bf;
    gemm_fused_hidden<<<dim3(2, 500), 256, 0, stream>>>(
        fsrc, WT_fij, t_ni, cs_e, cs_src, cs_dst,
        bias_h + (size_t)l * 256, attn_h + (size_t)l * 256, fdst, exb);
    node_gather_hidden<<<4000, 256, 0, stream>>>(t_ni, row_ptr, cs_src, exb, n_cur, n_bf);
  }

  // final layer: head-permuted weights/tables; fused f-GEMM in CSR order
  transpose4p<<<dim3(128, 16, 4), dim3(16, 16), 0, stream>>>(
      Wnode_l, Wni_l, Wnj_l, Wfij_l, WTF);
  permute_ba<<<8, 256, 0, stream>>>(bias_l, attn_l, biasp, attnp);
  gemm_abt<<<dim3(16, 125, 3), 256, 0, stream>>>(n_bf, WTF_ni, WTF_nj, WTF_node,
                                                 t_ni, t_nj, t_node, 2048);
  for (int p0 = 0; p0 < NE; p0 += ech) {
    gemm_fused_final<<<dim3(16, ech / 128), 256, 0, stream>>>(
        p0, f_bf, WTF_fij, t_ni, t_nj, cs_e, cs_src, cs_dst,
        biasp, attnp, f_bf, out_f, part);
    logit_reduce<<<ech / 4, 256, 0, stream>>>(p0, ech, part, exb);
  }
  node_gather_final_all<<<4000, 256, 0, stream>>>(t_node, row_ptr, cs_src,
                                                  exb, n_cur, out_n);
}